// Round 1
// baseline (602.677 us; speedup 1.0000x reference)
//
#include <hip/hip_runtime.h>
#include <math.h>

// Problem constants (match reference)
#define KB 16      // batch
#define KT 256     // num_tf
#define KG 1024    // num_genes
#define KP 16      // peaks per gene
#define KN 4096    // num_gos
#define KGO 6      // go_dim
#define KH 2       // heads
#define KC 4       // out channels
#define KE 65536   // edges
#define KOUT 32    // num outputs

__device__ __forceinline__ float lrelu(float x, float s) { return x >= 0.f ? x : s * x; }

// ---------------------------------------------------------------------------
// K1 (v3): per-gene subnet xcat[b][g] = lrelu(sum_{t,p} x*W + b).
// Block = (gene-chunk gc of 32 genes, batch b), 512 threads = 4 t-quarters
// x 128 threads. Per t-iteration each quarter reads a CONTIGUOUS 2 KB
// segment of x. 512 blocks -> 2 blocks/CU (was exactly 1/CU at 256 blocks;
// any scheduler imbalance doubled the tail). W_sub chunk (512 KB) shared by
// the 16 consecutive b-blocks of a gc -> L2/L3 served. Reduction tree is
// identical to v2 (same t-quarters, same quad shuffle) -> bit-exact.
// ---------------------------------------------------------------------------
__global__ __launch_bounds__(512) void k1_subnet(const float* __restrict__ x,
                                                 const float* __restrict__ Wsub,
                                                 const float* __restrict__ bsub,
                                                 float* __restrict__ xcat) {
    int tid = threadIdx.x;
    int sub = tid >> 7;           // t-quarter 0..3
    int u   = tid & 127;
    int gc  = blockIdx.x >> 4;    // 0..31  (gc-major: 16 b-blocks share W chunk)
    int b   = blockIdx.x & 15;
    int g0  = gc * 32;
    int g   = g0 + (u >> 2);
    int p4  = (u & 3) * 4;
    const float* xb = x + (size_t)b * (KT * KG * KP) + (size_t)g0 * KP + u * 4;
    const float* wg = Wsub + (size_t)g * (KT * KP) + p4;
    float4 acc = make_float4(0.f, 0.f, 0.f, 0.f);
    int t0 = sub * 64;
#pragma unroll 8
    for (int i = 0; i < 64; ++i) {
        int t = t0 + i;
        float4 xv = *(const float4*)(xb + (size_t)t * (KG * KP));
        float4 wv = *(const float4*)(wg + (size_t)t * KP);
        acc.x += xv.x * wv.x; acc.y += xv.y * wv.y;
        acc.z += xv.z * wv.z; acc.w += xv.w * wv.w;
    }
    float s = acc.x + acc.y + acc.z + acc.w;
    s += __shfl_xor(s, 1, 64);
    s += __shfl_xor(s, 2, 64);    // quad-reduce: 4 lanes of one gene
    __shared__ float part[4][32];
    if ((u & 3) == 0) part[sub][u >> 2] = s;
    __syncthreads();
    if (tid < 32) {
        float v = part[0][tid] + part[1][tid] + part[2][tid] + part[3][tid];
        xcat[b * KG + g0 + tid] = lrelu(v + bsub[g0 + tid], 0.01f);
    }
}

// ---------------------------------------------------------------------------
// K2 (v2): masked fc1. Two new traffic cuts:
//  (a) mask_rep = repeat(mask, 6, axis=0): rows 6m..6m+5 are identical.
//      Read the canonical row 6*(j/6) ONCE per group into registers (mreg)
//      -> mask HBM traffic 96 MiB -> ~17 MiB.
//  (b) mask is 5% dense. Predicate the w float4 load on any(mv != 0):
//      ~81.5% of w chunks are never fetched (exec-masked lanes fetch no
//      lines). Skipped terms contribute exactly +0.0 -> bit-exact.
// Block = 4 waves; wave wid owns batches b0=wid*4..+3, x_cat slice lives in
// registers. 4 waves share w/mask rows -> L1 hits.
// ---------------------------------------------------------------------------
__global__ __launch_bounds__(256) void k2_fc1(const float* __restrict__ w,
                                              const float* __restrict__ mask,
                                              const float* __restrict__ bias,
                                              const float* __restrict__ xcat, // [b][g]
                                              float* __restrict__ ht) {      // [n][b][d]
    int wid = threadIdx.x >> 6;
    int lane = threadIdx.x & 63;
    int b0 = wid * 4;
    float4 xcr[4][4];  // [bb][i] -> x_cat[b0+bb][i*256 + lane*4 .. +3]
#pragma unroll
    for (int bb = 0; bb < 4; ++bb)
#pragma unroll
        for (int i = 0; i < 4; ++i)
            xcr[bb][i] = *(const float4*)(xcat + (b0 + bb) * KG + i * 256 + lane * 4);

    int mj_cur = -1;
    float4 mreg[4];
    for (int r = 0; r < 16; ++r) {
        int j = blockIdx.x * 16 + r;        // row of (w*mask), j < 24576
        int mj = j / 6;                     // mask_rep row group
        if (mj != mj_cur) {                 // wave-uniform branch
            const float* mr = mask + (size_t)(mj * 6) * KG;  // canonical row
#pragma unroll
            for (int i = 0; i < 4; ++i)
                mreg[i] = *(const float4*)(mr + i * 256 + lane * 4);
            mj_cur = mj;
        }
        const float* wr = w + (size_t)j * KG;
        float acc0 = 0.f, acc1 = 0.f, acc2 = 0.f, acc3 = 0.f;
#pragma unroll
        for (int i = 0; i < 4; ++i) {
            float4 mv = mreg[i];
            if (mv.x != 0.f || mv.y != 0.f || mv.z != 0.f || mv.w != 0.f) {
                float4 wv = *(const float4*)(wr + i * 256 + lane * 4);
                float px = wv.x * mv.x, py = wv.y * mv.y, pz = wv.z * mv.z, pw = wv.w * mv.w;
                acc0 += px * xcr[0][i].x + py * xcr[0][i].y + pz * xcr[0][i].z + pw * xcr[0][i].w;
                acc1 += px * xcr[1][i].x + py * xcr[1][i].y + pz * xcr[1][i].z + pw * xcr[1][i].w;
                acc2 += px * xcr[2][i].x + py * xcr[2][i].y + pz * xcr[2][i].z + pw * xcr[2][i].w;
                acc3 += px * xcr[3][i].x + py * xcr[3][i].y + pz * xcr[3][i].z + pw * xcr[3][i].w;
            }
        }
#pragma unroll
        for (int m = 1; m < 64; m <<= 1) {
            acc0 += __shfl_xor(acc0, m, 64);
            acc1 += __shfl_xor(acc1, m, 64);
            acc2 += __shfl_xor(acc2, m, 64);
            acc3 += __shfl_xor(acc3, m, 64);
        }
        if (lane == 0) {
            float bj = bias[j];
            int d = j >> 12;           // j / N
            int n = j & 4095;          // j % N
            float* hp = ht + ((size_t)n * KB) * KGO + d;
            hp[(b0 + 0) * KGO] = lrelu(acc0 + bj, 0.01f);
            hp[(b0 + 1) * KGO] = lrelu(acc1 + bj, 0.01f);
            hp[(b0 + 2) * KGO] = lrelu(acc2 + bj, 0.01f);
            hp[(b0 + 3) * KGO] = lrelu(acc3 + bj, 0.01f);
        }
    }
}

// ---------------------------------------------------------------------------
// K3: hn = h @ gat_weight, plus attention dot products s_i, s_j per node.
// One thread per (n,b).
// ---------------------------------------------------------------------------
__global__ __launch_bounds__(256) void k3_gatw(const float* __restrict__ ht,
                                               const float* __restrict__ gw,   // [6][8]
                                               const float* __restrict__ att,  // [2][8]
                                               float* __restrict__ hn,         // [n][b][h][c]
                                               float* __restrict__ si,
                                               float* __restrict__ sj) {
    __shared__ float cgw[48];
    __shared__ float catt[16];
    int t = threadIdx.x;
    if (t < 48) cgw[t] = gw[t];
    else if (t < 64) catt[t - 48] = att[t - 48];
    __syncthreads();
    int idx = blockIdx.x * 256 + t;  // n*16 + b
    float h6[6];
#pragma unroll
    for (int d = 0; d < 6; ++d) h6[d] = ht[(size_t)idx * KGO + d];
    float o[8];
#pragma unroll
    for (int hc = 0; hc < 8; ++hc) {
        float v = 0.f;
#pragma unroll
        for (int d = 0; d < 6; ++d) v += h6[d] * cgw[d * 8 + hc];
        o[hc] = v;
        hn[(size_t)idx * 8 + hc] = v;
    }
#pragma unroll
    for (int hh = 0; hh < 2; ++hh) {
        float vi = 0.f, vj = 0.f;
#pragma unroll
        for (int c = 0; c < 4; ++c) {
            vi += o[hh * 4 + c] * catt[hh * 8 + c];       // att[:, :C]  (x_i)
            vj += o[hh * 4 + c] * catt[hh * 8 + 4 + c];   // att[:, C:]  (x_j)
        }
        si[idx * 2 + hh] = vi;
        sj[idx * 2 + hh] = vj;
    }
}

// ---------------------------------------------------------------------------
// K4a/b/c: CSR build (histogram, exclusive scan, scatter). The edge-dtype
// detect (int64 vs int32) is now folded into k4a/k4c per-block: each block
// checks the odd (hi) int32 words of its own 256 edges. int64 inputs with
// values < 2^31 have all hi words zero; for int32 inputs those words are
// real edge values in [0,4096) -> P(all 256 zero) ~ 4096^-256. Removes the
// k0 dispatch + its device-wide drain.
// ---------------------------------------------------------------------------
__global__ __launch_bounds__(256) void k4a_hist(const int* __restrict__ e32,
                                                int* __restrict__ cnt) {
    __shared__ int smode;
    int t = threadIdx.x;
    int e = blockIdx.x * 256 + t;
    int hi = e32[2 * e + 1];
    if (t == 0) smode = 1;
    __syncthreads();
    if (hi != 0) smode = 0;   // benign race: all writers store 0
    __syncthreads();
    int mode = smode;
    int d = mode ? e32[2 * (KE + e)] : e32[KE + e];
    atomicAdd(&cnt[d], 1);
}

__global__ __launch_bounds__(1024) void k4b_scan(const int* __restrict__ cnt,
                                                 int* __restrict__ off,
                                                 int* __restrict__ cur) {
    __shared__ int buf[2][1024];
    int t = threadIdx.x;
    int c0 = cnt[t * 4 + 0], c1 = cnt[t * 4 + 1], c2 = cnt[t * 4 + 2], c3 = cnt[t * 4 + 3];
    int s = c0 + c1 + c2 + c3;
    buf[0][t] = s;
    __syncthreads();
    int pb = 0;
    for (int d = 1; d < 1024; d <<= 1) {
        int v = buf[pb][t];
        if (t >= d) v += buf[pb][t - d];
        buf[1 - pb][t] = v;
        pb = 1 - pb;
        __syncthreads();
    }
    int incl = buf[pb][t];
    int base = incl - s;  // exclusive prefix
    int o0 = base, o1 = base + c0, o2 = base + c0 + c1, o3 = base + c0 + c1 + c2;
    off[t * 4 + 0] = o0; off[t * 4 + 1] = o1; off[t * 4 + 2] = o2; off[t * 4 + 3] = o3;
    cur[t * 4 + 0] = o0; cur[t * 4 + 1] = o1; cur[t * 4 + 2] = o2; cur[t * 4 + 3] = o3;
    if (t == 1023) off[KN] = incl;
}

__global__ __launch_bounds__(256) void k4c_scatter(const int* __restrict__ e32,
                                                   int* __restrict__ cur,
                                                   int* __restrict__ csr) {
    __shared__ int smode;
    int t = threadIdx.x;
    int e = blockIdx.x * 256 + t;
    int hi = e32[2 * e + 1];
    if (t == 0) smode = 1;
    __syncthreads();
    if (hi != 0) smode = 0;
    __syncthreads();
    int mode = smode;
    int d = mode ? e32[2 * (KE + e)] : e32[KE + e];
    int s = mode ? e32[2 * e] : e32[e];
    int p = atomicAdd(&cur[d], 1);
    csr[p] = s;
}

// ---------------------------------------------------------------------------
// K5: per-destination-node GAT aggregation. Block per node n; thread groups
// of 8 own one (b,h) pair. Pass 1: segment max (exact, like reference).
// Pass 2: exp-sum + weighted accumulation of hn[src]. Softmax-normalize,
// divide by degree, mean over heads, + bias. Output aggr[b][c*N + n].
// ---------------------------------------------------------------------------
__global__ __launch_bounds__(256) void k5_gat(const int* __restrict__ offs,
                                              const int* __restrict__ csr,
                                              const float* __restrict__ si,
                                              const float* __restrict__ sj,
                                              const float* __restrict__ hn,
                                              const float* __restrict__ gbias,
                                              float* __restrict__ aggr) {
    int n = blockIdx.x;
    int t = threadIdx.x;
    int p = t >> 3;          // (b,h) pair, 0..31
    int s = t & 7;
    int b = p >> 1, h = p & 1;
    int off = offs[n];
    int deg = offs[n + 1] - off;
    __shared__ float red[32][4];
    float l = 0.f, a0 = 0.f, a1 = 0.f, a2 = 0.f, a3 = 0.f;
    if (deg > 0) {
        float sib = si[(n * KB + b) * 2 + h];
        float m = -1e30f;
        for (int i = s; i < deg; i += 8) {
            int sv = csr[off + i];
            float a = sib + sj[(sv * KB + b) * 2 + h];
            a = a >= 0.f ? a : 0.2f * a;
            m = fmaxf(m, a);
        }
        m = fmaxf(m, __shfl_xor(m, 1, 64));
        m = fmaxf(m, __shfl_xor(m, 2, 64));
        m = fmaxf(m, __shfl_xor(m, 4, 64));
        for (int i = s; i < deg; i += 8) {
            int sv = csr[off + i];
            float a = sib + sj[(sv * KB + b) * 2 + h];
            a = a >= 0.f ? a : 0.2f * a;
            float wgt = expf(a - m);
            l += wgt;
            float4 hv = *(const float4*)(hn + ((size_t)(sv * KB + b)) * 8 + h * 4);
            a0 += wgt * hv.x; a1 += wgt * hv.y; a2 += wgt * hv.z; a3 += wgt * hv.w;
        }
#pragma unroll
        for (int d = 1; d <= 4; d <<= 1) {
            l  += __shfl_xor(l,  d, 64);
            a0 += __shfl_xor(a0, d, 64);
            a1 += __shfl_xor(a1, d, 64);
            a2 += __shfl_xor(a2, d, 64);
            a3 += __shfl_xor(a3, d, 64);
        }
    }
    if (s == 0) {
        float inv = (deg > 0) ? 1.f / l : 0.f;
        red[p][0] = a0 * inv; red[p][1] = a1 * inv;
        red[p][2] = a2 * inv; red[p][3] = a3 * inv;
    }
    __syncthreads();
    if (t < 64) {
        int bb = t >> 2, c = t & 3;
        float v = gbias[c];
        if (deg > 0)
            v += 0.5f * (red[bb * 2 + 0][c] + red[bb * 2 + 1][c]) / (float)deg;
        aggr[bb * (KC * KN) + c * KN + n] = v;
    }
}

// ---------------------------------------------------------------------------
// K6: readout. Block per (b,k): 16384-elem dot of lrelu(aggr[b]) with
// out_weight row k.
// ---------------------------------------------------------------------------
__global__ __launch_bounds__(256) void k6_out(const float* __restrict__ aggr,
                                              const float* __restrict__ ow,
                                              const float* __restrict__ obias,
                                              float* __restrict__ out) {
    int b = blockIdx.x >> 5;
    int k = blockIdx.x & 31;
    int t = threadIdx.x;
    const float* ar = aggr + (size_t)b * (KC * KN);
    const float* wr = ow + (size_t)k * (KC * KN);
    float sum = 0.f;
#pragma unroll 4
    for (int i = 0; i < 16; ++i) {
        int j = (i * 256 + t) * 4;
        float4 av = *(const float4*)(ar + j);
        float4 wv = *(const float4*)(wr + j);
        av.x = lrelu(av.x, 0.01f); av.y = lrelu(av.y, 0.01f);
        av.z = lrelu(av.z, 0.01f); av.w = lrelu(av.w, 0.01f);
        sum += av.x * wv.x + av.y * wv.y + av.z * wv.z + av.w * wv.w;
    }
#pragma unroll
    for (int d = 32; d > 0; d >>= 1) sum += __shfl_down(sum, d, 64);
    __shared__ float wsum[4];
    if ((t & 63) == 0) wsum[t >> 6] = sum;
    __syncthreads();
    if (t == 0) out[b * KOUT + k] = wsum[0] + wsum[1] + wsum[2] + wsum[3] + obias[k];
}

// ---------------------------------------------------------------------------
extern "C" void kernel_launch(void* const* d_in, const int* in_sizes, int n_in,
                              void* d_out, int out_size, void* d_ws, size_t ws_size,
                              hipStream_t stream) {
    const float* x     = (const float*)d_in[0];
    const int*   e32   = (const int*)d_in[1];
    const float* Wsub  = (const float*)d_in[2];
    const float* bsub  = (const float*)d_in[3];
    const float* fc1w  = (const float*)d_in[4];
    const float* maskr = (const float*)d_in[5];
    const float* fc1b  = (const float*)d_in[6];
    const float* gatw  = (const float*)d_in[7];
    const float* gata  = (const float*)d_in[8];
    const float* gatb  = (const float*)d_in[9];
    const float* outw  = (const float*)d_in[10];
    const float* outb  = (const float*)d_in[11];
    float* out = (float*)d_out;

    // Workspace layout (all 16-float aligned; ~6.2 MB total)
    float* ws   = (float*)d_ws;
    float* xcat = ws;                              // [B][G]        16384
    float* ht   = xcat + KB * KG;                  // [N][B][GO]    393216
    float* hn   = ht + (size_t)KN * KB * KGO;      // [N][B][H][C]  524288
    float* si   = hn + (size_t)KN * KB * KH * KC;  // [N][B][H]     131072
    float* sj   = si + (size_t)KN * KB * KH;       //               131072
    float* aggr = sj + (size_t)KN * KB * KH;       // [B][C][N]     262144
    int* icnt  = (int*)(aggr + (size_t)KB * KC * KN);  // N
    int* ioff  = icnt + KN;                            // N+1 (padded 16)
    int* icur  = ioff + (KN + 16);                     // N
    int* icsr  = icur + KN;                            // E

    k1_subnet<<<512, 512, 0, stream>>>(x, Wsub, bsub, xcat);
    k2_fc1<<<(KN * KGO) / 16, 256, 0, stream>>>(fc1w, maskr, fc1b, xcat, ht);
    k3_gatw<<<(KN * KB) / 256, 256, 0, stream>>>(ht, gatw, gata, hn, si, sj);
    hipMemsetAsync(icnt, 0, KN * sizeof(int), stream);
    k4a_hist<<<KE / 256, 256, 0, stream>>>(e32, icnt);
    k4b_scan<<<1, 1024, 0, stream>>>(icnt, ioff, icur);
    k4c_scatter<<<KE / 256, 256, 0, stream>>>(e32, icur, icsr);
    k5_gat<<<KN, 256, 0, stream>>>(ioff, icsr, si, sj, hn, gatb, aggr);
    k6_out<<<KB * KOUT, 256, 0, stream>>>(aggr, outw, outb, out);
}

// Round 2
// 543.598 us; speedup vs baseline: 1.1087x; 1.1087x over previous
//
#include <hip/hip_runtime.h>
#include <math.h>

// Problem constants (match reference)
#define KB 16      // batch
#define KT 256     // num_tf
#define KG 1024    // num_genes
#define KP 16      // peaks per gene
#define KN 4096    // num_gos
#define KGO 6      // go_dim
#define KH 2       // heads
#define KC 4       // out channels
#define KE 65536   // edges
#define KOUT 32    // num outputs

__device__ __forceinline__ float lrelu(float x, float s) { return x >= 0.f ? x : s * x; }

// ---------------------------------------------------------------------------
// K1 (v2 — reverted to round-0 measured-good geometry): per-gene subnet
// xcat[b][g] = lrelu(sum_{t,p} x*W + b).
// Block = (gene-chunk gc of 64 genes, batch b), 1024 threads = 4 t-quarters
// x 256 threads. Per t-iteration each quarter reads a CONTIGUOUS 4 KB
// segment of x. W_sub chunk (1 MB) is shared by the 16 consecutive b-blocks
// of a gc -> L2/L3 served. (Round-1's 512x512 + unroll 8 regrid regressed;
// this is the baseline-measured layout, bit-exact reduction tree.)
// ---------------------------------------------------------------------------
__global__ __launch_bounds__(1024) void k1_subnet(const float* __restrict__ x,
                                                  const float* __restrict__ Wsub,
                                                  const float* __restrict__ bsub,
                                                  float* __restrict__ xcat) {
    int tid = threadIdx.x;
    int sub = tid >> 8;           // t-quarter 0..3
    int u   = tid & 255;
    int gc  = blockIdx.x >> 4;    // 0..15  (gc-major: 16 b-blocks share W chunk)
    int b   = blockIdx.x & 15;
    int g0  = gc * 64;
    int g   = g0 + (u >> 2);
    int p4  = (u & 3) * 4;
    const float* xb = x + (size_t)b * (KT * KG * KP) + (size_t)g0 * KP + u * 4;
    const float* wg = Wsub + (size_t)g * (KT * KP) + p4;
    float4 acc = make_float4(0.f, 0.f, 0.f, 0.f);
    int t0 = sub * 64;
#pragma unroll 4
    for (int i = 0; i < 64; ++i) {
        int t = t0 + i;
        float4 xv = *(const float4*)(xb + (size_t)t * (KG * KP));
        float4 wv = *(const float4*)(wg + (size_t)t * KP);
        acc.x += xv.x * wv.x; acc.y += xv.y * wv.y;
        acc.z += xv.z * wv.z; acc.w += xv.w * wv.w;
    }
    float s = acc.x + acc.y + acc.z + acc.w;
    s += __shfl_xor(s, 1, 64);
    s += __shfl_xor(s, 2, 64);    // quad-reduce: 4 lanes of one gene
    __shared__ float part[4][64];
    if ((u & 3) == 0) part[sub][u >> 2] = s;
    __syncthreads();
    if (tid < 64) {
        float v = part[0][tid] + part[1][tid] + part[2][tid] + part[3][tid];
        xcat[b * KG + g0 + tid] = lrelu(v + bsub[g0 + tid], 0.01f);
    }
}

// ---------------------------------------------------------------------------
// K2 (v3): masked fc1. ONE traffic cut vs baseline, coalesced-only:
//   mask_rep = repeat(mask, 6, axis=0): rows 6m..6m+5 identical. Read the
//   canonical row 6*(j/6) ONCE per group into registers (block-uniform
//   branch, full sequential 4 KB row read) -> mask HBM 96 MiB -> ~22 MiB.
// Round-1's per-lane predicated w load is REVERTED: lane-divergent skips
// turned the w stream into random 64B-line fetches (low DRAM efficiency) —
// net regression. w is streamed unconditionally again.
// Block = 4 waves; wave wid owns batches b0=wid*4..+3, x_cat in registers.
// ---------------------------------------------------------------------------
__global__ __launch_bounds__(256) void k2_fc1(const float* __restrict__ w,
                                              const float* __restrict__ mask,
                                              const float* __restrict__ bias,
                                              const float* __restrict__ xcat, // [b][g]
                                              float* __restrict__ ht) {      // [n][b][d]
    int wid = threadIdx.x >> 6;
    int lane = threadIdx.x & 63;
    int b0 = wid * 4;
    float4 xcr[4][4];  // [bb][i] -> x_cat[b0+bb][i*256 + lane*4 .. +3]
#pragma unroll
    for (int bb = 0; bb < 4; ++bb)
#pragma unroll
        for (int i = 0; i < 4; ++i)
            xcr[bb][i] = *(const float4*)(xcat + (b0 + bb) * KG + i * 256 + lane * 4);

    int mj_cur = -1;
    float4 mreg[4];
    for (int r = 0; r < 16; ++r) {
        int j = blockIdx.x * 16 + r;        // row of (w*mask), j < 24576
        int mj = j / 6;                     // mask_rep group (block-uniform)
        if (mj != mj_cur) {
            const float* mr = mask + (size_t)(mj * 6) * KG;  // canonical row
#pragma unroll
            for (int i = 0; i < 4; ++i)
                mreg[i] = *(const float4*)(mr + i * 256 + lane * 4);
            mj_cur = mj;
        }
        const float* wr = w + (size_t)j * KG;
        float acc0 = 0.f, acc1 = 0.f, acc2 = 0.f, acc3 = 0.f;
#pragma unroll
        for (int i = 0; i < 4; ++i) {
            float4 wv = *(const float4*)(wr + i * 256 + lane * 4);
            float4 mv = mreg[i];
            float px = wv.x * mv.x, py = wv.y * mv.y, pz = wv.z * mv.z, pw = wv.w * mv.w;
            acc0 += px * xcr[0][i].x + py * xcr[0][i].y + pz * xcr[0][i].z + pw * xcr[0][i].w;
            acc1 += px * xcr[1][i].x + py * xcr[1][i].y + pz * xcr[1][i].z + pw * xcr[1][i].w;
            acc2 += px * xcr[2][i].x + py * xcr[2][i].y + pz * xcr[2][i].z + pw * xcr[2][i].w;
            acc3 += px * xcr[3][i].x + py * xcr[3][i].y + pz * xcr[3][i].z + pw * xcr[3][i].w;
        }
#pragma unroll
        for (int m = 1; m < 64; m <<= 1) {
            acc0 += __shfl_xor(acc0, m, 64);
            acc1 += __shfl_xor(acc1, m, 64);
            acc2 += __shfl_xor(acc2, m, 64);
            acc3 += __shfl_xor(acc3, m, 64);
        }
        if (lane == 0) {
            float bj = bias[j];
            int d = j >> 12;           // j / N
            int n = j & 4095;          // j % N
            float* hp = ht + ((size_t)n * KB) * KGO + d;
            hp[(b0 + 0) * KGO] = lrelu(acc0 + bj, 0.01f);
            hp[(b0 + 1) * KGO] = lrelu(acc1 + bj, 0.01f);
            hp[(b0 + 2) * KGO] = lrelu(acc2 + bj, 0.01f);
            hp[(b0 + 3) * KGO] = lrelu(acc3 + bj, 0.01f);
        }
    }
}

// ---------------------------------------------------------------------------
// K3: hn = h @ gat_weight, plus attention dot products s_i, s_j per node.
// One thread per (n,b).
// ---------------------------------------------------------------------------
__global__ __launch_bounds__(256) void k3_gatw(const float* __restrict__ ht,
                                               const float* __restrict__ gw,   // [6][8]
                                               const float* __restrict__ att,  // [2][8]
                                               float* __restrict__ hn,         // [n][b][h][c]
                                               float* __restrict__ si,
                                               float* __restrict__ sj) {
    __shared__ float cgw[48];
    __shared__ float catt[16];
    int t = threadIdx.x;
    if (t < 48) cgw[t] = gw[t];
    else if (t < 64) catt[t - 48] = att[t - 48];
    __syncthreads();
    int idx = blockIdx.x * 256 + t;  // n*16 + b
    float h6[6];
#pragma unroll
    for (int d = 0; d < 6; ++d) h6[d] = ht[(size_t)idx * KGO + d];
    float o[8];
#pragma unroll
    for (int hc = 0; hc < 8; ++hc) {
        float v = 0.f;
#pragma unroll
        for (int d = 0; d < 6; ++d) v += h6[d] * cgw[d * 8 + hc];
        o[hc] = v;
        hn[(size_t)idx * 8 + hc] = v;
    }
#pragma unroll
    for (int hh = 0; hh < 2; ++hh) {
        float vi = 0.f, vj = 0.f;
#pragma unroll
        for (int c = 0; c < 4; ++c) {
            vi += o[hh * 4 + c] * catt[hh * 8 + c];       // att[:, :C]  (x_i)
            vj += o[hh * 4 + c] * catt[hh * 8 + 4 + c];   // att[:, C:]  (x_j)
        }
        si[idx * 2 + hh] = vi;
        sj[idx * 2 + hh] = vj;
    }
}

// ---------------------------------------------------------------------------
// K4a/b/c: CSR build (histogram, exclusive scan, scatter). Edge-dtype detect
// (int64 vs int32) folded in per-block: check hi int32 words of this block's
// 256 edges. int64 with values < 2^31 -> all hi words zero; int32 data makes
// those words real edge values in [0,4096) -> P(all 256 zero) ~ 4096^-256.
// ---------------------------------------------------------------------------
__global__ __launch_bounds__(256) void k4a_hist(const int* __restrict__ e32,
                                                int* __restrict__ cnt) {
    __shared__ int smode;
    int t = threadIdx.x;
    int e = blockIdx.x * 256 + t;
    int hi = e32[2 * e + 1];
    if (t == 0) smode = 1;
    __syncthreads();
    if (hi != 0) smode = 0;   // benign race: all writers store 0
    __syncthreads();
    int mode = smode;
    int d = mode ? e32[2 * (KE + e)] : e32[KE + e];
    atomicAdd(&cnt[d], 1);
}

__global__ __launch_bounds__(1024) void k4b_scan(const int* __restrict__ cnt,
                                                 int* __restrict__ off,
                                                 int* __restrict__ cur) {
    __shared__ int buf[2][1024];
    int t = threadIdx.x;
    int c0 = cnt[t * 4 + 0], c1 = cnt[t * 4 + 1], c2 = cnt[t * 4 + 2], c3 = cnt[t * 4 + 3];
    int s = c0 + c1 + c2 + c3;
    buf[0][t] = s;
    __syncthreads();
    int pb = 0;
    for (int d = 1; d < 1024; d <<= 1) {
        int v = buf[pb][t];
        if (t >= d) v += buf[pb][t - d];
        buf[1 - pb][t] = v;
        pb = 1 - pb;
        __syncthreads();
    }
    int incl = buf[pb][t];
    int base = incl - s;  // exclusive prefix
    int o0 = base, o1 = base + c0, o2 = base + c0 + c1, o3 = base + c0 + c1 + c2;
    off[t * 4 + 0] = o0; off[t * 4 + 1] = o1; off[t * 4 + 2] = o2; off[t * 4 + 3] = o3;
    cur[t * 4 + 0] = o0; cur[t * 4 + 1] = o1; cur[t * 4 + 2] = o2; cur[t * 4 + 3] = o3;
    if (t == 1023) off[KN] = incl;
}

__global__ __launch_bounds__(256) void k4c_scatter(const int* __restrict__ e32,
                                                   int* __restrict__ cur,
                                                   int* __restrict__ csr) {
    __shared__ int smode;
    int t = threadIdx.x;
    int e = blockIdx.x * 256 + t;
    int hi = e32[2 * e + 1];
    if (t == 0) smode = 1;
    __syncthreads();
    if (hi != 0) smode = 0;
    __syncthreads();
    int mode = smode;
    int d = mode ? e32[2 * (KE + e)] : e32[KE + e];
    int s = mode ? e32[2 * e] : e32[e];
    int p = atomicAdd(&cur[d], 1);
    csr[p] = s;
}

// ---------------------------------------------------------------------------
// K5: per-destination-node GAT aggregation. Block per node n; thread groups
// of 8 own one (b,h) pair. Pass 1: segment max (exact, like reference).
// Pass 2: exp-sum + weighted accumulation of hn[src]. Softmax-normalize,
// divide by degree, mean over heads, + bias. Output aggr[b][c*N + n].
// ---------------------------------------------------------------------------
__global__ __launch_bounds__(256) void k5_gat(const int* __restrict__ offs,
                                              const int* __restrict__ csr,
                                              const float* __restrict__ si,
                                              const float* __restrict__ sj,
                                              const float* __restrict__ hn,
                                              const float* __restrict__ gbias,
                                              float* __restrict__ aggr) {
    int n = blockIdx.x;
    int t = threadIdx.x;
    int p = t >> 3;          // (b,h) pair, 0..31
    int s = t & 7;
    int b = p >> 1, h = p & 1;
    int off = offs[n];
    int deg = offs[n + 1] - off;
    __shared__ float red[32][4];
    float l = 0.f, a0 = 0.f, a1 = 0.f, a2 = 0.f, a3 = 0.f;
    if (deg > 0) {
        float sib = si[(n * KB + b) * 2 + h];
        float m = -1e30f;
        for (int i = s; i < deg; i += 8) {
            int sv = csr[off + i];
            float a = sib + sj[(sv * KB + b) * 2 + h];
            a = a >= 0.f ? a : 0.2f * a;
            m = fmaxf(m, a);
        }
        m = fmaxf(m, __shfl_xor(m, 1, 64));
        m = fmaxf(m, __shfl_xor(m, 2, 64));
        m = fmaxf(m, __shfl_xor(m, 4, 64));
        for (int i = s; i < deg; i += 8) {
            int sv = csr[off + i];
            float a = sib + sj[(sv * KB + b) * 2 + h];
            a = a >= 0.f ? a : 0.2f * a;
            float wgt = expf(a - m);
            l += wgt;
            float4 hv = *(const float4*)(hn + ((size_t)(sv * KB + b)) * 8 + h * 4);
            a0 += wgt * hv.x; a1 += wgt * hv.y; a2 += wgt * hv.z; a3 += wgt * hv.w;
        }
#pragma unroll
        for (int d = 1; d <= 4; d <<= 1) {
            l  += __shfl_xor(l,  d, 64);
            a0 += __shfl_xor(a0, d, 64);
            a1 += __shfl_xor(a1, d, 64);
            a2 += __shfl_xor(a2, d, 64);
            a3 += __shfl_xor(a3, d, 64);
        }
    }
    if (s == 0) {
        float inv = (deg > 0) ? 1.f / l : 0.f;
        red[p][0] = a0 * inv; red[p][1] = a1 * inv;
        red[p][2] = a2 * inv; red[p][3] = a3 * inv;
    }
    __syncthreads();
    if (t < 64) {
        int bb = t >> 2, c = t & 3;
        float v = gbias[c];
        if (deg > 0)
            v += 0.5f * (red[bb * 2 + 0][c] + red[bb * 2 + 1][c]) / (float)deg;
        aggr[bb * (KC * KN) + c * KN + n] = v;
    }
}

// ---------------------------------------------------------------------------
// K6: readout. Block per (b,k): 16384-elem dot of lrelu(aggr[b]) with
// out_weight row k.
// ---------------------------------------------------------------------------
__global__ __launch_bounds__(256) void k6_out(const float* __restrict__ aggr,
                                              const float* __restrict__ ow,
                                              const float* __restrict__ obias,
                                              float* __restrict__ out) {
    int b = blockIdx.x >> 5;
    int k = blockIdx.x & 31;
    int t = threadIdx.x;
    const float* ar = aggr + (size_t)b * (KC * KN);
    const float* wr = ow + (size_t)k * (KC * KN);
    float sum = 0.f;
#pragma unroll 4
    for (int i = 0; i < 16; ++i) {
        int j = (i * 256 + t) * 4;
        float4 av = *(const float4*)(ar + j);
        float4 wv = *(const float4*)(wr + j);
        av.x = lrelu(av.x, 0.01f); av.y = lrelu(av.y, 0.01f);
        av.z = lrelu(av.z, 0.01f); av.w = lrelu(av.w, 0.01f);
        sum += av.x * wv.x + av.y * wv.y + av.z * wv.z + av.w * wv.w;
    }
#pragma unroll
    for (int d = 32; d > 0; d >>= 1) sum += __shfl_down(sum, d, 64);
    __shared__ float wsum[4];
    if ((t & 63) == 0) wsum[t >> 6] = sum;
    __syncthreads();
    if (t == 0) out[b * KOUT + k] = wsum[0] + wsum[1] + wsum[2] + wsum[3] + obias[k];
}

// ---------------------------------------------------------------------------
extern "C" void kernel_launch(void* const* d_in, const int* in_sizes, int n_in,
                              void* d_out, int out_size, void* d_ws, size_t ws_size,
                              hipStream_t stream) {
    const float* x     = (const float*)d_in[0];
    const int*   e32   = (const int*)d_in[1];
    const float* Wsub  = (const float*)d_in[2];
    const float* bsub  = (const float*)d_in[3];
    const float* fc1w  = (const float*)d_in[4];
    const float* maskr = (const float*)d_in[5];
    const float* fc1b  = (const float*)d_in[6];
    const float* gatw  = (const float*)d_in[7];
    const float* gata  = (const float*)d_in[8];
    const float* gatb  = (const float*)d_in[9];
    const float* outw  = (const float*)d_in[10];
    const float* outb  = (const float*)d_in[11];
    float* out = (float*)d_out;

    // Workspace layout (all 16-float aligned; ~6.2 MB total)
    float* ws   = (float*)d_ws;
    float* xcat = ws;                              // [B][G]        16384
    float* ht   = xcat + KB * KG;                  // [N][B][GO]    393216
    float* hn   = ht + (size_t)KN * KB * KGO;      // [N][B][H][C]  524288
    float* si   = hn + (size_t)KN * KB * KH * KC;  // [N][B][H]     131072
    float* sj   = si + (size_t)KN * KB * KH;       //               131072
    float* aggr = sj + (size_t)KN * KB * KH;       // [B][C][N]     262144
    int* icnt  = (int*)(aggr + (size_t)KB * KC * KN);  // N
    int* ioff  = icnt + KN;                            // N+1 (padded 16)
    int* icur  = ioff + (KN + 16);                     // N
    int* icsr  = icur + KN;                            // E

    k1_subnet<<<256, 1024, 0, stream>>>(x, Wsub, bsub, xcat);
    k2_fc1<<<(KN * KGO) / 16, 256, 0, stream>>>(fc1w, maskr, fc1b, xcat, ht);
    k3_gatw<<<(KN * KB) / 256, 256, 0, stream>>>(ht, gatw, gata, hn, si, sj);
    hipMemsetAsync(icnt, 0, KN * sizeof(int), stream);
    k4a_hist<<<KE / 256, 256, 0, stream>>>(e32, icnt);
    k4b_scan<<<1, 1024, 0, stream>>>(icnt, ioff, icur);
    k4c_scatter<<<KE / 256, 256, 0, stream>>>(e32, icur, icsr);
    k5_gat<<<KN, 256, 0, stream>>>(ioff, icsr, si, sj, hn, gatb, aggr);
    k6_out<<<KB * KOUT, 256, 0, stream>>>(aggr, outw, outb, out);
}

// Round 3
// 538.336 us; speedup vs baseline: 1.1195x; 1.0098x over previous
//
#include <hip/hip_runtime.h>
#include <math.h>

// Problem constants (match reference)
#define KB 16      // batch
#define KT 256     // num_tf
#define KG 1024    // num_genes
#define KP 16      // peaks per gene
#define KN 4096    // num_gos
#define KGO 6      // go_dim
#define KH 2       // heads
#define KC 4       // out channels
#define KE 65536   // edges
#define KOUT 32    // num outputs

__device__ __forceinline__ float lrelu(float x, float s) { return x >= 0.f ? x : s * x; }

// ---------------------------------------------------------------------------
// K1 (v4): per-gene subnet xcat[b][g] = lrelu(sum_{t,p} x*W + b).
// Geometry identical to the measured-good v2 (block = (gc of 64 genes, b),
// 1024 threads = 4 t-quarters x 256, contiguous 4 KB x segments, bit-exact
// reduction tree). Two additions:
//  (a) XCD swizzle: wk = (bid&7)*32 + (bid>>3). HW round-robins consecutive
//      bids across the 8 XCDs, so this places all 16 b-blocks of one gene-
//      chunk on ONE XCD -> its 1 MB W_sub chunk is fetched into that L2
//      once instead of 8x (134 MB -> 16.7 MB of L2-miss traffic).
//  (b) Block 256 (tail) zeroes the K4 histogram, removing the
//      hipMemsetAsync dispatch (K4a runs 2 dispatches later).
// ---------------------------------------------------------------------------
__global__ __launch_bounds__(1024) void k1_subnet(const float* __restrict__ x,
                                                  const float* __restrict__ Wsub,
                                                  const float* __restrict__ bsub,
                                                  float* __restrict__ xcat,
                                                  int* __restrict__ cnt) {
    if (blockIdx.x >= 256) {      // tail block: zero CSR histogram (16 KB)
        int t = threadIdx.x;
#pragma unroll
        for (int i = 0; i < 4; ++i) cnt[t + i * 1024] = 0;
        return;
    }
    int wk  = ((blockIdx.x & 7) << 5) | (blockIdx.x >> 3);  // XCD-group swizzle
    int tid = threadIdx.x;
    int sub = tid >> 8;           // t-quarter 0..3
    int u   = tid & 255;
    int gc  = wk >> 4;            // 0..15  (all 16 b-blocks of gc on one XCD)
    int b   = wk & 15;
    int g0  = gc * 64;
    int g   = g0 + (u >> 2);
    int p4  = (u & 3) * 4;
    const float* xb = x + (size_t)b * (KT * KG * KP) + (size_t)g0 * KP + u * 4;
    const float* wg = Wsub + (size_t)g * (KT * KP) + p4;
    float4 acc = make_float4(0.f, 0.f, 0.f, 0.f);
    int t0 = sub * 64;
#pragma unroll 4
    for (int i = 0; i < 64; ++i) {
        int t = t0 + i;
        float4 xv = *(const float4*)(xb + (size_t)t * (KG * KP));
        float4 wv = *(const float4*)(wg + (size_t)t * KP);
        acc.x += xv.x * wv.x; acc.y += xv.y * wv.y;
        acc.z += xv.z * wv.z; acc.w += xv.w * wv.w;
    }
    float s = acc.x + acc.y + acc.z + acc.w;
    s += __shfl_xor(s, 1, 64);
    s += __shfl_xor(s, 2, 64);    // quad-reduce: 4 lanes of one gene
    __shared__ float part[4][64];
    if ((u & 3) == 0) part[sub][u >> 2] = s;
    __syncthreads();
    if (tid < 64) {
        float v = part[0][tid] + part[1][tid] + part[2][tid] + part[3][tid];
        xcat[b * KG + g0 + tid] = lrelu(v + bsub[g0 + tid], 0.01f);
    }
}

// ---------------------------------------------------------------------------
// K2 (v3, unchanged from round 2 — measured good): masked fc1.
// mask_rep dedup: rows 6m..6m+5 identical -> read canonical row once per
// group (block-uniform, coalesced) -> mask HBM 96 MiB -> ~22 MiB. w streamed
// unconditionally (predication measured as a regression in round 1).
// ---------------------------------------------------------------------------
__global__ __launch_bounds__(256) void k2_fc1(const float* __restrict__ w,
                                              const float* __restrict__ mask,
                                              const float* __restrict__ bias,
                                              const float* __restrict__ xcat, // [b][g]
                                              float* __restrict__ ht) {      // [n][b][d]
    int wid = threadIdx.x >> 6;
    int lane = threadIdx.x & 63;
    int b0 = wid * 4;
    float4 xcr[4][4];  // [bb][i] -> x_cat[b0+bb][i*256 + lane*4 .. +3]
#pragma unroll
    for (int bb = 0; bb < 4; ++bb)
#pragma unroll
        for (int i = 0; i < 4; ++i)
            xcr[bb][i] = *(const float4*)(xcat + (b0 + bb) * KG + i * 256 + lane * 4);

    int mj_cur = -1;
    float4 mreg[4];
    for (int r = 0; r < 16; ++r) {
        int j = blockIdx.x * 16 + r;        // row of (w*mask), j < 24576
        int mj = j / 6;                     // mask_rep group (block-uniform)
        if (mj != mj_cur) {
            const float* mr = mask + (size_t)(mj * 6) * KG;  // canonical row
#pragma unroll
            for (int i = 0; i < 4; ++i)
                mreg[i] = *(const float4*)(mr + i * 256 + lane * 4);
            mj_cur = mj;
        }
        const float* wr = w + (size_t)j * KG;
        float acc0 = 0.f, acc1 = 0.f, acc2 = 0.f, acc3 = 0.f;
#pragma unroll
        for (int i = 0; i < 4; ++i) {
            float4 wv = *(const float4*)(wr + i * 256 + lane * 4);
            float4 mv = mreg[i];
            float px = wv.x * mv.x, py = wv.y * mv.y, pz = wv.z * mv.z, pw = wv.w * mv.w;
            acc0 += px * xcr[0][i].x + py * xcr[0][i].y + pz * xcr[0][i].z + pw * xcr[0][i].w;
            acc1 += px * xcr[1][i].x + py * xcr[1][i].y + pz * xcr[1][i].z + pw * xcr[1][i].w;
            acc2 += px * xcr[2][i].x + py * xcr[2][i].y + pz * xcr[2][i].z + pw * xcr[2][i].w;
            acc3 += px * xcr[3][i].x + py * xcr[3][i].y + pz * xcr[3][i].z + pw * xcr[3][i].w;
        }
#pragma unroll
        for (int m = 1; m < 64; m <<= 1) {
            acc0 += __shfl_xor(acc0, m, 64);
            acc1 += __shfl_xor(acc1, m, 64);
            acc2 += __shfl_xor(acc2, m, 64);
            acc3 += __shfl_xor(acc3, m, 64);
        }
        if (lane == 0) {
            float bj = bias[j];
            int d = j >> 12;           // j / N
            int n = j & 4095;          // j % N
            float* hp = ht + ((size_t)n * KB) * KGO + d;
            hp[(b0 + 0) * KGO] = lrelu(acc0 + bj, 0.01f);
            hp[(b0 + 1) * KGO] = lrelu(acc1 + bj, 0.01f);
            hp[(b0 + 2) * KGO] = lrelu(acc2 + bj, 0.01f);
            hp[(b0 + 3) * KGO] = lrelu(acc3 + bj, 0.01f);
        }
    }
}

// ---------------------------------------------------------------------------
// K3: hn = h @ gat_weight, plus attention dot products s_i, s_j per node.
// One thread per (n,b).
// ---------------------------------------------------------------------------
__global__ __launch_bounds__(256) void k3_gatw(const float* __restrict__ ht,
                                               const float* __restrict__ gw,   // [6][8]
                                               const float* __restrict__ att,  // [2][8]
                                               float* __restrict__ hn,         // [n][b][h][c]
                                               float* __restrict__ si,
                                               float* __restrict__ sj) {
    __shared__ float cgw[48];
    __shared__ float catt[16];
    int t = threadIdx.x;
    if (t < 48) cgw[t] = gw[t];
    else if (t < 64) catt[t - 48] = att[t - 48];
    __syncthreads();
    int idx = blockIdx.x * 256 + t;  // n*16 + b
    float h6[6];
#pragma unroll
    for (int d = 0; d < 6; ++d) h6[d] = ht[(size_t)idx * KGO + d];
    float o[8];
#pragma unroll
    for (int hc = 0; hc < 8; ++hc) {
        float v = 0.f;
#pragma unroll
        for (int d = 0; d < 6; ++d) v += h6[d] * cgw[d * 8 + hc];
        o[hc] = v;
        hn[(size_t)idx * 8 + hc] = v;
    }
#pragma unroll
    for (int hh = 0; hh < 2; ++hh) {
        float vi = 0.f, vj = 0.f;
#pragma unroll
        for (int c = 0; c < 4; ++c) {
            vi += o[hh * 4 + c] * catt[hh * 8 + c];       // att[:, :C]  (x_i)
            vj += o[hh * 4 + c] * catt[hh * 8 + 4 + c];   // att[:, C:]  (x_j)
        }
        si[idx * 2 + hh] = vi;
        sj[idx * 2 + hh] = vj;
    }
}

// ---------------------------------------------------------------------------
// K4a/b/c: CSR build (histogram, exclusive scan, scatter). Edge-dtype detect
// (int64 vs int32) folded in per-block: check hi int32 words of this block's
// 256 edges. int64 with values < 2^31 -> all hi words zero; int32 data makes
// those words real edge values in [0,4096) -> P(all 256 zero) ~ 4096^-256.
// Histogram zeroing now happens in K1's tail block (no memset dispatch).
// ---------------------------------------------------------------------------
__global__ __launch_bounds__(256) void k4a_hist(const int* __restrict__ e32,
                                                int* __restrict__ cnt) {
    __shared__ int smode;
    int t = threadIdx.x;
    int e = blockIdx.x * 256 + t;
    int hi = e32[2 * e + 1];
    if (t == 0) smode = 1;
    __syncthreads();
    if (hi != 0) smode = 0;   // benign race: all writers store 0
    __syncthreads();
    int mode = smode;
    int d = mode ? e32[2 * (KE + e)] : e32[KE + e];
    atomicAdd(&cnt[d], 1);
}

__global__ __launch_bounds__(1024) void k4b_scan(const int* __restrict__ cnt,
                                                 int* __restrict__ off,
                                                 int* __restrict__ cur) {
    __shared__ int buf[2][1024];
    int t = threadIdx.x;
    int c0 = cnt[t * 4 + 0], c1 = cnt[t * 4 + 1], c2 = cnt[t * 4 + 2], c3 = cnt[t * 4 + 3];
    int s = c0 + c1 + c2 + c3;
    buf[0][t] = s;
    __syncthreads();
    int pb = 0;
    for (int d = 1; d < 1024; d <<= 1) {
        int v = buf[pb][t];
        if (t >= d) v += buf[pb][t - d];
        buf[1 - pb][t] = v;
        pb = 1 - pb;
        __syncthreads();
    }
    int incl = buf[pb][t];
    int base = incl - s;  // exclusive prefix
    int o0 = base, o1 = base + c0, o2 = base + c0 + c1, o3 = base + c0 + c1 + c2;
    off[t * 4 + 0] = o0; off[t * 4 + 1] = o1; off[t * 4 + 2] = o2; off[t * 4 + 3] = o3;
    cur[t * 4 + 0] = o0; cur[t * 4 + 1] = o1; cur[t * 4 + 2] = o2; cur[t * 4 + 3] = o3;
    if (t == 1023) off[KN] = incl;
}

__global__ __launch_bounds__(256) void k4c_scatter(const int* __restrict__ e32,
                                                   int* __restrict__ cur,
                                                   int* __restrict__ csr) {
    __shared__ int smode;
    int t = threadIdx.x;
    int e = blockIdx.x * 256 + t;
    int hi = e32[2 * e + 1];
    if (t == 0) smode = 1;
    __syncthreads();
    if (hi != 0) smode = 0;
    __syncthreads();
    int mode = smode;
    int d = mode ? e32[2 * (KE + e)] : e32[KE + e];
    int s = mode ? e32[2 * e] : e32[e];
    int p = atomicAdd(&cur[d], 1);
    csr[p] = s;
}

// ---------------------------------------------------------------------------
// K5: per-destination-node GAT aggregation. Block per node n; thread groups
// of 8 own one (b,h) pair. Pass 1: segment max (exact, like reference).
// Pass 2: exp-sum + weighted accumulation of hn[src]. Softmax-normalize,
// divide by degree, mean over heads, + bias. Output aggr[b][c*N + n].
// ---------------------------------------------------------------------------
__global__ __launch_bounds__(256) void k5_gat(const int* __restrict__ offs,
                                              const int* __restrict__ csr,
                                              const float* __restrict__ si,
                                              const float* __restrict__ sj,
                                              const float* __restrict__ hn,
                                              const float* __restrict__ gbias,
                                              float* __restrict__ aggr) {
    int n = blockIdx.x;
    int t = threadIdx.x;
    int p = t >> 3;          // (b,h) pair, 0..31
    int s = t & 7;
    int b = p >> 1, h = p & 1;
    int off = offs[n];
    int deg = offs[n + 1] - off;
    __shared__ float red[32][4];
    float l = 0.f, a0 = 0.f, a1 = 0.f, a2 = 0.f, a3 = 0.f;
    if (deg > 0) {
        float sib = si[(n * KB + b) * 2 + h];
        float m = -1e30f;
        for (int i = s; i < deg; i += 8) {
            int sv = csr[off + i];
            float a = sib + sj[(sv * KB + b) * 2 + h];
            a = a >= 0.f ? a : 0.2f * a;
            m = fmaxf(m, a);
        }
        m = fmaxf(m, __shfl_xor(m, 1, 64));
        m = fmaxf(m, __shfl_xor(m, 2, 64));
        m = fmaxf(m, __shfl_xor(m, 4, 64));
        for (int i = s; i < deg; i += 8) {
            int sv = csr[off + i];
            float a = sib + sj[(sv * KB + b) * 2 + h];
            a = a >= 0.f ? a : 0.2f * a;
            float wgt = expf(a - m);
            l += wgt;
            float4 hv = *(const float4*)(hn + ((size_t)(sv * KB + b)) * 8 + h * 4);
            a0 += wgt * hv.x; a1 += wgt * hv.y; a2 += wgt * hv.z; a3 += wgt * hv.w;
        }
#pragma unroll
        for (int d = 1; d <= 4; d <<= 1) {
            l  += __shfl_xor(l,  d, 64);
            a0 += __shfl_xor(a0, d, 64);
            a1 += __shfl_xor(a1, d, 64);
            a2 += __shfl_xor(a2, d, 64);
            a3 += __shfl_xor(a3, d, 64);
        }
    }
    if (s == 0) {
        float inv = (deg > 0) ? 1.f / l : 0.f;
        red[p][0] = a0 * inv; red[p][1] = a1 * inv;
        red[p][2] = a2 * inv; red[p][3] = a3 * inv;
    }
    __syncthreads();
    if (t < 64) {
        int bb = t >> 2, c = t & 3;
        float v = gbias[c];
        if (deg > 0)
            v += 0.5f * (red[bb * 2 + 0][c] + red[bb * 2 + 1][c]) / (float)deg;
        aggr[bb * (KC * KN) + c * KN + n] = v;
    }
}

// ---------------------------------------------------------------------------
// K6: readout. Block per (b,k): 16384-elem dot of lrelu(aggr[b]) with
// out_weight row k.
// ---------------------------------------------------------------------------
__global__ __launch_bounds__(256) void k6_out(const float* __restrict__ aggr,
                                              const float* __restrict__ ow,
                                              const float* __restrict__ obias,
                                              float* __restrict__ out) {
    int b = blockIdx.x >> 5;
    int k = blockIdx.x & 31;
    int t = threadIdx.x;
    const float* ar = aggr + (size_t)b * (KC * KN);
    const float* wr = ow + (size_t)k * (KC * KN);
    float sum = 0.f;
#pragma unroll 4
    for (int i = 0; i < 16; ++i) {
        int j = (i * 256 + t) * 4;
        float4 av = *(const float4*)(ar + j);
        float4 wv = *(const float4*)(wr + j);
        av.x = lrelu(av.x, 0.01f); av.y = lrelu(av.y, 0.01f);
        av.z = lrelu(av.z, 0.01f); av.w = lrelu(av.w, 0.01f);
        sum += av.x * wv.x + av.y * wv.y + av.z * wv.z + av.w * wv.w;
    }
#pragma unroll
    for (int d = 32; d > 0; d >>= 1) sum += __shfl_down(sum, d, 64);
    __shared__ float wsum[4];
    if ((t & 63) == 0) wsum[t >> 6] = sum;
    __syncthreads();
    if (t == 0) out[b * KOUT + k] = wsum[0] + wsum[1] + wsum[2] + wsum[3] + obias[k];
}

// ---------------------------------------------------------------------------
extern "C" void kernel_launch(void* const* d_in, const int* in_sizes, int n_in,
                              void* d_out, int out_size, void* d_ws, size_t ws_size,
                              hipStream_t stream) {
    const float* x     = (const float*)d_in[0];
    const int*   e32   = (const int*)d_in[1];
    const float* Wsub  = (const float*)d_in[2];
    const float* bsub  = (const float*)d_in[3];
    const float* fc1w  = (const float*)d_in[4];
    const float* maskr = (const float*)d_in[5];
    const float* fc1b  = (const float*)d_in[6];
    const float* gatw  = (const float*)d_in[7];
    const float* gata  = (const float*)d_in[8];
    const float* gatb  = (const float*)d_in[9];
    const float* outw  = (const float*)d_in[10];
    const float* outb  = (const float*)d_in[11];
    float* out = (float*)d_out;

    // Workspace layout (all 16-float aligned; ~6.2 MB total)
    float* ws   = (float*)d_ws;
    float* xcat = ws;                              // [B][G]        16384
    float* ht   = xcat + KB * KG;                  // [N][B][GO]    393216
    float* hn   = ht + (size_t)KN * KB * KGO;      // [N][B][H][C]  524288
    float* si   = hn + (size_t)KN * KB * KH * KC;  // [N][B][H]     131072
    float* sj   = si + (size_t)KN * KB * KH;       //               131072
    float* aggr = sj + (size_t)KN * KB * KH;       // [B][C][N]     262144
    int* icnt  = (int*)(aggr + (size_t)KB * KC * KN);  // N
    int* ioff  = icnt + KN;                            // N+1 (padded 16)
    int* icur  = ioff + (KN + 16);                     // N
    int* icsr  = icur + KN;                            // E

    k1_subnet<<<257, 1024, 0, stream>>>(x, Wsub, bsub, xcat, icnt);
    k2_fc1<<<(KN * KGO) / 16, 256, 0, stream>>>(fc1w, maskr, fc1b, xcat, ht);
    k3_gatw<<<(KN * KB) / 256, 256, 0, stream>>>(ht, gatw, gata, hn, si, sj);
    k4a_hist<<<KE / 256, 256, 0, stream>>>(e32, icnt);
    k4b_scan<<<1, 1024, 0, stream>>>(icnt, ioff, icur);
    k4c_scatter<<<KE / 256, 256, 0, stream>>>(e32, icur, icsr);
    k5_gat<<<KN, 256, 0, stream>>>(ioff, icsr, si, sj, hn, gatb, aggr);
    k6_out<<<KB * KOUT, 256, 0, stream>>>(aggr, outw, outb, out);
}